// Round 4
// baseline (237.792 us; speedup 1.0000x reference)
//
#include <hip/hip_runtime.h>
#include <stdint.h>

#define NIMG 8
#define NCLS 80
#define HF 100
#define WF 152
#define NPTS (HF*WF)          // 15200
#define NPC (NPTS*NCLS)       // 1216000
#define NF4 (NPC/4)           // 304000 float4 groups per image
#define TOPK 1000
#define NSH 8                 // candidate shards per image (kills same-address atomic contention)
#define SHCAP 512             // slots per shard (expected ~250, cap = +17 sigma)
#define SORTN 4096            // max total candidates = NSH*SHCAP
#define LBUF 1024             // per-block LDS candidate buffer
#define POSTK 100
#define HBLK 297              // ceil(NF4/1024): 256 thr x 4 float4 groups = 4096 elems/block
#define RBLK (SORTN/256)      // 16 rank blocks per image

// ---- workspace layout (bytes) ----
static constexpr size_t B_H1    = 0;                              // u32 [8][4096]
static constexpr size_t B_CNT   = B_H1 + (size_t)NIMG*4096*4;     // u32 [8][NSH] shard counters
static constexpr size_t B_META  = B_CNT + (size_t)NIMG*NSH*4;     // u32 [8][4] {c_above, T14, -, -}
static constexpr size_t B_SKEY  = B_META + NIMG*4*4;              // u64 [8][1024] rank-ordered keys (0 = empty)
static constexpr size_t B_ZEND  = B_SKEY + (size_t)NIMG*1024*8;   // memset 0 through here
static constexpr size_t B_CTRS  = (B_ZEND + 15) & ~(size_t)15;    // f32 [8][15200] sigm(centerness)
static constexpr size_t B_CAND  = (B_CTRS + (size_t)NIMG*NPTS*4 + 15) & ~(size_t)15; // u64 [8][NSH][SHCAP]
static constexpr size_t B_BOX   = B_CAND + (size_t)NIMG*NSH*SHCAP*8; // f32 [8][TOPK][4]
static constexpr size_t B_OBOX  = B_BOX + (size_t)NIMG*TOPK*16;   // f32 [8][TOPK][4]
static constexpr size_t B_SC    = B_OBOX + (size_t)NIMG*TOPK*16;  // f32 [8][TOPK]
static constexpr size_t B_VAL   = B_SC + (size_t)NIMG*TOPK*4;     // u32 [8][TOPK]
static constexpr size_t B_LAB   = B_VAL + (size_t)NIMG*TOPK*4;    // u32 [8][TOPK]
static constexpr size_t B_CBASE = B_LAB + (size_t)NIMG*TOPK*4;    // u32 [8][81]
static constexpr size_t B_CLIST = B_CBASE + (size_t)NIMG*81*4;    // u32 [8][TOPK]
static constexpr size_t B_KEEP  = B_CLIST + (size_t)NIMG*TOPK*4;  // u32 [8][TOPK]

__device__ __forceinline__ float sigm(float x){ return 1.0f / (1.0f + expf(-x)); }

// precompute sigmoid(centerness) once: 8*15200 = 121600 elems (= 30400 float4)
__global__ void __launch_bounds__(256)
k_ctrsig(const float* __restrict__ ctr, float* __restrict__ ctr_sig){
  int i4 = blockIdx.x * 256 + threadIdx.x;
  if (i4 < NIMG*NPTS/4){
    float4 v = ((const float4*)ctr)[i4];
    float4 o;
    o.x = sigm(v.x); o.y = sigm(v.y); o.z = sigm(v.z); o.w = sigm(v.w);
    ((float4*)ctr_sig)[i4] = o;
  }
}

// single-level 14-bit histogram: scores in (0,1) => __float_as_uint(s)>>18 < 4064
__global__ void __launch_bounds__(256)
k_hist(const float* __restrict__ box_cls, const float* __restrict__ ctr_sig,
       uint32_t* __restrict__ h1){
  __shared__ uint32_t h[4096];
  for (int i = threadIdx.x; i < 4096; i += 256) h[i] = 0;
  __syncthreads();
  const int n = blockIdx.y;
  const float4* cls4 = (const float4*)(box_cls + (size_t)n * NPC);
  const float* cs = ctr_sig + (size_t)n * NPTS;
  const int base4 = blockIdx.x * 1024 + threadIdx.x;
  float4 a[4], b[4];
  bool ok[4];
  #pragma unroll
  for (int k = 0; k < 4; ++k){
    int i4 = base4 + k * 256;
    ok[k] = (i4 < NF4);
    if (ok[k]){
      a[k] = cls4[i4];
      uint32_t p0 = ((uint32_t)(i4 << 2)) % (uint32_t)NPTS;
      b[k] = *(const float4*)(cs + p0);
    }
  }
  // forbid the register allocator from sinking the loads into the compute loop:
  // all 8 vector loads must be in flight before any use (MLP).
  __builtin_amdgcn_sched_barrier(0);
  #pragma unroll
  for (int k = 0; k < 4; ++k){
    if (!ok[k]) continue;
    float sv[4] = {a[k].x, a[k].y, a[k].z, a[k].w};
    float cv[4] = {b[k].x, b[k].y, b[k].z, b[k].w};
    #pragma unroll
    for (int j = 0; j < 4; ++j){
      float s = sigm(sv[j]);
      if (s > 0.05f){
        float sc = s * cv[j];
        if (sc > 0.0f) atomicAdd(&h[__float_as_uint(sc) >> 18], 1u);
      }
    }
  }
  __syncthreads();
  uint32_t* g = h1 + (size_t)n * 4096;
  for (int i = threadIdx.x; i < 4096; i += 256){
    uint32_t v = h[i];
    if (v) atomicAdd(&g[i], v);
  }
}

// find 14-bit threshold bin T14: count(prefix > T14) < TOPK <= count(prefix >= T14)
__global__ void k_scan(const uint32_t* __restrict__ h1, uint32_t* __restrict__ meta){
  const int n = blockIdx.x;
  const uint32_t* h = h1 + (size_t)n * 4096;
  __shared__ uint32_t psum[256];
  __shared__ uint32_t suff[256];
  const int t = threadIdx.x;
  uint32_t s = 0;
  #pragma unroll
  for (int i = 0; i < 16; ++i) s += h[t * 16 + i];
  psum[t] = s;
  __syncthreads();
  if (t == 0){
    uint32_t acc = 0;
    for (int seg = 255; seg >= 0; --seg){ suff[seg] = acc; acc += psum[seg]; }
  }
  __syncthreads();
  if (suff[t] < TOPK && suff[t] + psum[t] >= TOPK){
    uint32_t acc = suff[t];
    for (int b = t * 16 + 15; b >= t * 16; --b){
      uint32_t hb = h[b];
      if (acc + hb >= TOPK){
        meta[n * 4 + 0] = acc;           // count strictly above threshold bin
        meta[n * 4 + 1] = (uint32_t)b;   // T14
        break;
      }
      acc += hb;
    }
  }
}

// collect candidates with 14-bit prefix >= T14.
// Per-block LDS aggregation + ONE sharded global atomic per block.
__global__ void __launch_bounds__(256)
k_collect(const float* __restrict__ box_cls, const float* __restrict__ ctr_sig,
          const uint32_t* __restrict__ meta,
          uint32_t* __restrict__ cnt, uint64_t* __restrict__ cand){
  __shared__ uint64_t buf[LBUF];
  __shared__ uint32_t lcnt;
  __shared__ uint32_t gbase;
  const int n = blockIdx.y;
  const uint32_t T = meta[n * 4 + 1];
  if (threadIdx.x == 0) lcnt = 0;
  __syncthreads();
  const float4* cls4 = (const float4*)(box_cls + (size_t)n * NPC);
  const float* cs = ctr_sig + (size_t)n * NPTS;
  const int base4 = blockIdx.x * 1024 + threadIdx.x;
  float4 a[4], b[4];
  int p0a[4], ca[4];
  bool ok[4];
  #pragma unroll
  for (int k = 0; k < 4; ++k){
    int i4 = base4 + k * 256;
    ok[k] = (i4 < NF4);
    if (ok[k]){
      a[k] = cls4[i4];
      uint32_t e0 = (uint32_t)(i4 << 2);
      uint32_t c = e0 / (uint32_t)NPTS;      // constant within a 4-aligned group
      uint32_t p0 = e0 - c * (uint32_t)NPTS;
      ca[k] = (int)c; p0a[k] = (int)p0;
      b[k] = *(const float4*)(cs + p0);
    }
  }
  __builtin_amdgcn_sched_barrier(0);         // keep all 8 loads issued up-front (MLP)
  #pragma unroll
  for (int k = 0; k < 4; ++k){
    if (!ok[k]) continue;
    float sv[4] = {a[k].x, a[k].y, a[k].z, a[k].w};
    float cv[4] = {b[k].x, b[k].y, b[k].z, b[k].w};
    #pragma unroll
    for (int j = 0; j < 4; ++j){
      float s = sigm(sv[j]);
      if (s > 0.05f){
        float sc = s * cv[j];
        if (sc > 0.0f){
          uint32_t bits = __float_as_uint(sc);
          if ((bits >> 18) >= T){
            uint32_t f = (uint32_t)(p0a[k] + j) * NCLS + (uint32_t)ca[k]; // ref flat idx
            uint32_t pos = atomicAdd(&lcnt, 1u);            // LDS atomic: ~7/block typical
            if (pos < LBUF)
              buf[pos] = ((uint64_t)bits << 32) | (uint64_t)(0xFFFFFFFFu - f);
          }
        }
      }
    }
  }
  __syncthreads();
  uint32_t c = lcnt; if (c > LBUF) c = LBUF;
  const int sh = blockIdx.x & (NSH - 1);
  if (threadIdx.x == 0 && c) gbase = atomicAdd(&cnt[n * NSH + sh], c);  // 1 atomic/block
  __syncthreads();
  for (uint32_t i = threadIdx.x; i < c; i += 256){
    uint32_t p = gbase + i;
    if (p < SHCAP) cand[(((size_t)n * NSH + sh) << 9) + p] = buf[i];
  }
}

// rank-based selection: rank(x) = #{y: key_y > key_x} is x's exact sorted position
// (keys unique: index embedded). Barrier-free LDS broadcast scan replaces the
// 66-barrier-step bitonic sort that was 96us on one CU/image.
__global__ void __launch_bounds__(256)
k_rank(const uint32_t* __restrict__ cnt, const uint64_t* __restrict__ cand,
       uint64_t* __restrict__ skey){
  __shared__ alignas(16) uint64_t keys[SORTN + 4];
  __shared__ uint32_t cs_s[NSH], pre_s[NSH + 1];
  const int n = blockIdx.y;
  const int t = threadIdx.x;
  if (t == 0){
    uint32_t acc = 0;
    for (int s = 0; s < NSH; ++s){
      uint32_t c = cnt[n * NSH + s]; if (c > SHCAP) c = SHCAP;
      cs_s[s] = c; pre_s[s] = acc; acc += c;
    }
    pre_s[NSH] = acc;
  }
  __syncthreads();
  const int total = (int)pre_s[NSH];
  const int base = blockIdx.x * 256;
  if (base >= total) return;                 // block-uniform early exit
  // compact all shards into LDS (every active block keeps a full copy)
  for (int i = t; i < SORTN; i += 256){
    int s = i >> 9, j = i & (SHCAP - 1);
    if ((uint32_t)j < cs_s[s])
      keys[pre_s[s] + j] = cand[(((size_t)n * NSH + s) << 9) + j];
  }
  if (t < 4) keys[total + t] = 0ull;         // pad for unroll-4 (0 never outranks)
  __syncthreads();
  const int g = base + t;
  const uint64_t my = (g < total) ? keys[g] : 0ull;
  uint32_t rank = 0;
  const int tot4 = (total + 3) & ~3;
  for (int i = 0; i < tot4; i += 4){         // same-address broadcast reads: conflict-free
    rank += (keys[i]     > my) ? 1u : 0u;
    rank += (keys[i + 1] > my) ? 1u : 0u;
    rank += (keys[i + 2] > my) ? 1u : 0u;
    rank += (keys[i + 3] > my) ? 1u : 0u;
  }
  if (g < total && rank < TOPK)
    skey[(size_t)n * 1024 + rank] = my;      // ranks in [0,total) are a permutation
}

// decode boxes for the 1000 rank-ordered keys, then stable-partition by class
__global__ void __launch_bounds__(1024)
k_decode(const uint64_t* __restrict__ skey,
         const float* __restrict__ locations, const float* __restrict__ box_reg,
         const float* __restrict__ im_info,
         float* __restrict__ boxw, float* __restrict__ oboxw, float* __restrict__ scw,
         uint32_t* __restrict__ valw, uint32_t* __restrict__ labw,
         uint32_t* __restrict__ cbase, uint32_t* __restrict__ clist){
  __shared__ alignas(4) uint8_t lab_s[TOPK];   // 0-based class per sorted slot
  __shared__ uint32_t cntc_s[NCLS];
  __shared__ uint32_t basec_s[NCLS + 1];
  const int n = blockIdx.x;
  const int t = threadIdx.x;
  if (t < TOPK){
    uint64_t kk = skey[(size_t)n * 1024 + t];
    uint32_t bits = (uint32_t)(kk >> 32);
    uint32_t fi = 0xFFFFFFFFu - (uint32_t)(kk & 0xFFFFFFFFull);
    float v = __uint_as_float(bits);
    int loc = 0, ci = 0;
    if (v > 0.0f){ loc = (int)(fi / NCLS); ci = (int)(fi - (uint32_t)loc * NCLS); }
    float px = locations[2 * loc], py = locations[2 * loc + 1];
    const float* rg = box_reg + (size_t)n * 4 * NPTS;
    float rl = rg[loc], rt = rg[NPTS + loc], rr = rg[2 * NPTS + loc], rb = rg[3 * NPTS + loc];
    float h_im = im_info[n * 2 + 0], w_im = im_info[n * 2 + 1];
    float x1 = fminf(fmaxf(px - rl, 0.0f), w_im - 1.0f);
    float y1 = fminf(fmaxf(py - rt, 0.0f), h_im - 1.0f);
    float x2 = fminf(fmaxf(px + rr, 0.0f), w_im - 1.0f);
    float y2 = fminf(fmaxf(py + rb, 0.0f), h_im - 1.0f);
    bool valid = (v > 0.0f) && (__fsub_rn(x2, x1) >= 0.0f) && (__fsub_rn(y2, y1) >= 0.0f);
    float scv = valid ? v : 0.0f;
    float lab = (float)(ci + 1);
    float off = __fmul_rn(lab, 100000.0f);   // CLASS_OFFSET, mul then add (no fma) like ref
    size_t b4 = ((size_t)n * TOPK + t) * 4;
    boxw[b4 + 0] = x1; boxw[b4 + 1] = y1; boxw[b4 + 2] = x2; boxw[b4 + 3] = y2;
    oboxw[b4 + 0] = __fadd_rn(x1, off); oboxw[b4 + 1] = __fadd_rn(y1, off);
    oboxw[b4 + 2] = __fadd_rn(x2, off); oboxw[b4 + 3] = __fadd_rn(y2, off);
    size_t b1 = (size_t)n * TOPK + t;
    scw[b1] = scv; valw[b1] = valid ? 1u : 0u; labw[b1] = (uint32_t)(ci + 1);
    lab_s[t] = (uint8_t)ci;
  }
  __syncthreads();
  // ---- stable partition by class: thread c handles class c ----
  if (t < NCLS){
    const uint32_t* l4 = (const uint32_t*)lab_s;
    uint32_t myc = (uint32_t)t, cn = 0;
    for (int j = 0; j < TOPK / 4; ++j){
      uint32_t w = l4[j];
      cn += ((w & 0xffu) == myc) + (((w >> 8) & 0xffu) == myc)
          + (((w >> 16) & 0xffu) == myc) + ((w >> 24) == myc);
    }
    cntc_s[t] = cn;
  }
  __syncthreads();
  if (t == 0){
    uint32_t acc = 0;
    for (int c = 0; c < NCLS; ++c){ basec_s[c] = acc; acc += cntc_s[c]; }
    basec_s[NCLS] = acc;
  }
  __syncthreads();
  if (t <= NCLS) cbase[n * (NCLS + 1) + t] = basec_s[t];
  if (t < NCLS){
    const uint32_t* l4 = (const uint32_t*)lab_s;
    uint32_t myc = (uint32_t)t, pos = basec_s[t];
    for (int j = 0; j < TOPK / 4; ++j){
      uint32_t w = l4[j];
      #pragma unroll
      for (int b = 0; b < 4; ++b){
        if (((w >> (8 * b)) & 0xffu) == myc)
          clist[(size_t)n * TOPK + pos++] = (uint32_t)(4 * j + b);
      }
    }
  }
}

// greedy NMS per (image,class); cross-class IoU is exactly 0 under the 1e5 offset
__global__ void __launch_bounds__(64)
k_nms(const uint32_t* __restrict__ cbase, const uint32_t* __restrict__ clist,
      const float* __restrict__ oboxw, const uint32_t* __restrict__ valw,
      uint32_t* __restrict__ keepw){
  const int n = blockIdx.y;
  const int c = blockIdx.x;
  const uint32_t base = cbase[n * (NCLS + 1) + c];
  const uint32_t kcnt = cbase[n * (NCLS + 1) + c + 1] - base;
  if (kcnt == 0) return;
  const int L = threadIdx.x;
  const uint32_t* lst = clist + (size_t)n * TOPK + base;
  if (kcnt <= 64){
    int gi = 0, kp = 0;
    float b0 = 0, b1 = 0, b2 = 0, b3 = 0, ar = 0;
    if (L < (int)kcnt){
      gi = (int)lst[L];
      size_t a4 = ((size_t)n * TOPK + gi) * 4;
      b0 = oboxw[a4 + 0]; b1 = oboxw[a4 + 1]; b2 = oboxw[a4 + 2]; b3 = oboxw[a4 + 3];
      kp = (valw[n * TOPK + gi] != 0) ? 1 : 0;
      ar = __fmul_rn(fmaxf(__fsub_rn(b2, b0), 0.0f), fmaxf(__fsub_rn(b3, b1), 0.0f));
    }
    for (int i = 0; i + 1 < (int)kcnt; ++i){
      int alive = __shfl(kp, i);
      float xi0 = __shfl(b0, i), xi1 = __shfl(b1, i), xi2 = __shfl(b2, i), xi3 = __shfl(b3, i);
      float ai = __shfl(ar, i);
      if (alive && L > i && kp){
        float ltx = fmaxf(xi0, b0), lty = fmaxf(xi1, b1);
        float rbx = fminf(xi2, b2), rby = fminf(xi3, b3);
        float w = fmaxf(__fsub_rn(rbx, ltx), 0.0f);
        float h = fmaxf(__fsub_rn(rby, lty), 0.0f);
        float inter = __fmul_rn(w, h);
        float den = __fadd_rn(__fsub_rn(__fadd_rn(ai, ar), inter), 1e-9f);
        if (inter / den > 0.6f) kp = 0;
      }
    }
    if (L < (int)kcnt) keepw[n * TOPK + gi] = (uint32_t)kp;
  } else if (L == 0){
    // slow path (kcnt > 64): sequential, correctness-only (statistically never hit)
    for (uint32_t i = 0; i < kcnt; ++i){
      int gi = (int)lst[i];
      keepw[n * TOPK + gi] = valw[n * TOPK + gi];
    }
    for (uint32_t i = 0; i < kcnt; ++i){
      int gi = (int)lst[i];
      if (!keepw[n * TOPK + gi]) continue;
      size_t a4 = ((size_t)n * TOPK + gi) * 4;
      float x0 = oboxw[a4], x1 = oboxw[a4 + 1], x2 = oboxw[a4 + 2], x3 = oboxw[a4 + 3];
      float ai = __fmul_rn(fmaxf(__fsub_rn(x2, x0), 0.0f), fmaxf(__fsub_rn(x3, x1), 0.0f));
      for (uint32_t j = i + 1; j < kcnt; ++j){
        int gj = (int)lst[j];
        if (!keepw[n * TOPK + gj]) continue;
        size_t c4 = ((size_t)n * TOPK + gj) * 4;
        float y0 = oboxw[c4], y1 = oboxw[c4 + 1], y2 = oboxw[c4 + 2], y3 = oboxw[c4 + 3];
        float aj = __fmul_rn(fmaxf(__fsub_rn(y2, y0), 0.0f), fmaxf(__fsub_rn(y3, y1), 0.0f));
        float ltx = fmaxf(x0, y0), lty = fmaxf(x1, y1);
        float rbx = fminf(x2, y2), rby = fminf(x3, y3);
        float w = fmaxf(__fsub_rn(rbx, ltx), 0.0f);
        float h = fmaxf(__fsub_rn(rby, lty), 0.0f);
        float inter = __fmul_rn(w, h);
        float den = __fadd_rn(__fsub_rn(__fadd_rn(ai, aj), inter), 1e-9f);
        if (inter / den > 0.6f) keepw[n * TOPK + gj] = 0;
      }
    }
  }
}

// compact kept (already score-sorted) entries via parallel prefix scan; first 100 rows out
__global__ void __launch_bounds__(256)
k_final(const uint32_t* __restrict__ keepw, const float* __restrict__ boxw,
        const uint32_t* __restrict__ labw, const float* __restrict__ scw,
        float* __restrict__ out){
  const int n = blockIdx.x;
  __shared__ uint16_t fi_s[TOPK];
  __shared__ uint32_t wsum[4];
  const int t = threadIdx.x;
  const int i0 = t * 4;
  uint32_t f[4];
  #pragma unroll
  for (int j = 0; j < 4; ++j)
    f[j] = (i0 + j < TOPK) ? keepw[n * TOPK + i0 + j] : 0u;
  uint32_t lsum = f[0] + f[1] + f[2] + f[3];
  uint32_t sc = lsum;
  #pragma unroll
  for (int d = 1; d < 64; d <<= 1){
    uint32_t v = __shfl_up(sc, d);
    if ((t & 63) >= d) sc += v;
  }
  if ((t & 63) == 63) wsum[t >> 6] = sc;
  __syncthreads();
  uint32_t base = sc - lsum;
  for (int w = 0; w < (t >> 6); ++w) base += wsum[w];
  uint32_t p = base;
  #pragma unroll
  for (int j = 0; j < 4; ++j){
    if (f[j]){ if (p < TOPK) fi_s[p] = (uint16_t)(i0 + j); ++p; }
  }
  __syncthreads();
  uint32_t total = wsum[0] + wsum[1] + wsum[2] + wsum[3];
  if (t < POSTK){
    float* row = out + ((size_t)n * POSTK + t) * 6;
    if (t < (int)total){
      int i = (int)fi_s[t];
      size_t b4 = ((size_t)n * TOPK + i) * 4;
      row[0] = boxw[b4]; row[1] = boxw[b4 + 1]; row[2] = boxw[b4 + 2]; row[3] = boxw[b4 + 3];
      row[4] = (float)labw[n * TOPK + i]; row[5] = scw[n * TOPK + i];
    } else {
      row[0] = 0.0f; row[1] = 0.0f; row[2] = 0.0f;
      row[3] = 0.0f; row[4] = 0.0f; row[5] = 0.0f;
    }
  }
}

extern "C" void kernel_launch(void* const* d_in, const int* in_sizes, int n_in,
                              void* d_out, int out_size, void* d_ws, size_t ws_size,
                              hipStream_t stream){
  const float* locations = (const float*)d_in[0];
  const float* box_cls   = (const float*)d_in[1];
  const float* box_reg   = (const float*)d_in[2];
  const float* ctr       = (const float*)d_in[3];
  const float* im_info   = (const float*)d_in[4];
  float* out = (float*)d_out;
  char* ws = (char*)d_ws;
  uint32_t* h1    = (uint32_t*)(ws + B_H1);
  uint32_t* cnt   = (uint32_t*)(ws + B_CNT);
  uint32_t* meta  = (uint32_t*)(ws + B_META);
  uint64_t* skey  = (uint64_t*)(ws + B_SKEY);
  float*    ctrs  = (float*)(ws + B_CTRS);
  uint64_t* cand  = (uint64_t*)(ws + B_CAND);
  float*    boxw  = (float*)(ws + B_BOX);
  float*    oboxw = (float*)(ws + B_OBOX);
  float*    scw   = (float*)(ws + B_SC);
  uint32_t* valw  = (uint32_t*)(ws + B_VAL);
  uint32_t* labw  = (uint32_t*)(ws + B_LAB);
  uint32_t* cbase = (uint32_t*)(ws + B_CBASE);
  uint32_t* clist = (uint32_t*)(ws + B_CLIST);
  uint32_t* keepw = (uint32_t*)(ws + B_KEEP);

  hipMemsetAsync(d_ws, 0, B_ZEND, stream);
  k_ctrsig<<<dim3((NIMG*NPTS/4 + 255)/256), 256, 0, stream>>>(ctr, ctrs);
  dim3 scang(HBLK, NIMG);
  k_hist<<<scang, 256, 0, stream>>>(box_cls, ctrs, h1);
  k_scan<<<NIMG, 256, 0, stream>>>(h1, meta);
  k_collect<<<scang, 256, 0, stream>>>(box_cls, ctrs, meta, cnt, cand);
  k_rank<<<dim3(RBLK, NIMG), 256, 0, stream>>>(cnt, cand, skey);
  k_decode<<<NIMG, 1024, 0, stream>>>(skey, locations, box_reg, im_info,
                                      boxw, oboxw, scw, valw, labw, cbase, clist);
  k_nms<<<dim3(NCLS, NIMG), 64, 0, stream>>>(cbase, clist, oboxw, valw, keepw);
  k_final<<<NIMG, 256, 0, stream>>>(keepw, boxw, labw, scw, out);
}

// Round 5
// 190.530 us; speedup vs baseline: 1.2481x; 1.2481x over previous
//
#include <hip/hip_runtime.h>
#include <stdint.h>

#define NIMG 8
#define NCLS 80
#define HF 100
#define WF 152
#define NPTS (HF*WF)          // 15200
#define NPC (NPTS*NCLS)       // 1216000
#define NF4 (NPC/4)           // 304000 float4 groups per image
#define TOPK 1000
#define NSH 8                 // candidate shards per image (kills same-address atomic contention)
#define SHCAP 512             // slots per shard (expected ~250, cap = +17 sigma)
#define SORTN 4096            // max total candidates = NSH*SHCAP
#define LBUF 1024             // per-block LDS candidate buffer
#define POSTK 100
#define HBLK 297              // ceil(NF4/1024): 256 thr x 4 float4 groups = 4096 elems/block
#define RBLK (SORTN/256)      // 16 rank blocks per image

// ---- workspace layout (bytes) ----
static constexpr size_t B_H1    = 0;                              // u32 [8][4096]
static constexpr size_t B_CNT   = B_H1 + (size_t)NIMG*4096*4;     // u32 [8][NSH] shard counters
static constexpr size_t B_META  = B_CNT + (size_t)NIMG*NSH*4;     // u32 [8][4] {c_above, T14, -, -}
static constexpr size_t B_BMAX  = B_META + NIMG*4*4;              // u32 [8][HBLK] per-block max bin
static constexpr size_t B_SKEY  = (B_BMAX + (size_t)NIMG*HBLK*4 + 7) & ~(size_t)7; // u64 [8][1024]
static constexpr size_t B_ZEND  = B_SKEY + (size_t)NIMG*1024*8;   // memset 0 through here
static constexpr size_t B_CTRS  = (B_ZEND + 15) & ~(size_t)15;    // f32 [8][15200] sigm(centerness)
static constexpr size_t B_CAND  = (B_CTRS + (size_t)NIMG*NPTS*4 + 15) & ~(size_t)15; // u64 [8][NSH][SHCAP]
static constexpr size_t B_BOX   = B_CAND + (size_t)NIMG*NSH*SHCAP*8; // f32 [8][TOPK][4]
static constexpr size_t B_OBOX  = B_BOX + (size_t)NIMG*TOPK*16;   // f32 [8][TOPK][4]
static constexpr size_t B_SC    = B_OBOX + (size_t)NIMG*TOPK*16;  // f32 [8][TOPK]
static constexpr size_t B_VAL   = B_SC + (size_t)NIMG*TOPK*4;     // u32 [8][TOPK]
static constexpr size_t B_LAB   = B_VAL + (size_t)NIMG*TOPK*4;    // u32 [8][TOPK]
static constexpr size_t B_KEEP  = B_LAB + (size_t)NIMG*TOPK*4;    // u32 [8][TOPK]

__device__ __forceinline__ float sigm(float x){ return 1.0f / (1.0f + expf(-x)); }

// precompute sigmoid(centerness) once: 8*15200 = 121600 elems (= 30400 float4)
__global__ void __launch_bounds__(256)
k_ctrsig(const float* __restrict__ ctr, float* __restrict__ ctr_sig){
  int i4 = blockIdx.x * 256 + threadIdx.x;
  if (i4 < NIMG*NPTS/4){
    float4 v = ((const float4*)ctr)[i4];
    float4 o;
    o.x = sigm(v.x); o.y = sigm(v.y); o.z = sigm(v.z); o.w = sigm(v.w);
    ((float4*)ctr_sig)[i4] = o;
  }
}

// single-level 14-bit histogram: scores in (0,1) => __float_as_uint(s)>>18 < 4064
// Also records the block-max bin so k_collect can skip candidate-free blocks.
__global__ void __launch_bounds__(256)
k_hist(const float* __restrict__ box_cls, const float* __restrict__ ctr_sig,
       uint32_t* __restrict__ h1, uint32_t* __restrict__ bmax){
  __shared__ uint32_t h[4096];
  __shared__ uint32_t smax;
  for (int i = threadIdx.x; i < 4096; i += 256) h[i] = 0;
  if (threadIdx.x == 0) smax = 0;
  __syncthreads();
  const int n = blockIdx.y;
  const float4* cls4 = (const float4*)(box_cls + (size_t)n * NPC);
  const float* cs = ctr_sig + (size_t)n * NPTS;
  const int base4 = blockIdx.x * 1024 + threadIdx.x;
  float4 a[4], b[4];
  bool ok[4];
  #pragma unroll
  for (int k = 0; k < 4; ++k){
    int i4 = base4 + k * 256;
    ok[k] = (i4 < NF4);
    if (ok[k]){
      a[k] = cls4[i4];
      uint32_t p0 = ((uint32_t)(i4 << 2)) % (uint32_t)NPTS;
      b[k] = *(const float4*)(cs + p0);
    }
  }
  // forbid sinking the loads into the compute loop: all 8 loads in flight (MLP)
  __builtin_amdgcn_sched_barrier(0);
  uint32_t vmax = 0;
  #pragma unroll
  for (int k = 0; k < 4; ++k){
    if (!ok[k]) continue;
    float sv[4] = {a[k].x, a[k].y, a[k].z, a[k].w};
    float cv[4] = {b[k].x, b[k].y, b[k].z, b[k].w};
    #pragma unroll
    for (int j = 0; j < 4; ++j){
      float s = sigm(sv[j]);
      if (s > 0.05f){
        float sc = s * cv[j];
        if (sc > 0.0f){
          uint32_t bin = __float_as_uint(sc) >> 18;
          atomicAdd(&h[bin], 1u);
          vmax = (bin > vmax) ? bin : vmax;
        }
      }
    }
  }
  if (vmax) atomicMax(&smax, vmax);
  __syncthreads();
  uint32_t* g = h1 + (size_t)n * 4096;
  for (int i = threadIdx.x; i < 4096; i += 256){
    uint32_t v = h[i];
    if (v) atomicAdd(&g[i], v);
  }
  if (threadIdx.x == 0) bmax[n * HBLK + blockIdx.x] = smax;
}

// find 14-bit threshold bin T14: count(prefix > T14) < TOPK <= count(prefix >= T14)
__global__ void k_scan(const uint32_t* __restrict__ h1, uint32_t* __restrict__ meta){
  const int n = blockIdx.x;
  const uint32_t* h = h1 + (size_t)n * 4096;
  __shared__ uint32_t psum[256];
  __shared__ uint32_t suff[256];
  const int t = threadIdx.x;
  uint32_t s = 0;
  #pragma unroll
  for (int i = 0; i < 16; ++i) s += h[t * 16 + i];
  psum[t] = s;
  __syncthreads();
  if (t == 0){
    uint32_t acc = 0;
    for (int seg = 255; seg >= 0; --seg){ suff[seg] = acc; acc += psum[seg]; }
  }
  __syncthreads();
  if (suff[t] < TOPK && suff[t] + psum[t] >= TOPK){
    uint32_t acc = suff[t];
    for (int b = t * 16 + 15; b >= t * 16; --b){
      uint32_t hb = h[b];
      if (acc + hb >= TOPK){
        meta[n * 4 + 0] = acc;           // count strictly above threshold bin
        meta[n * 4 + 1] = (uint32_t)b;   // T14
        break;
      }
      acc += hb;
    }
  }
}

// collect candidates with 14-bit prefix >= T14.
// Early-exit for blocks whose hist-pass max bin is below threshold (~55% of blocks).
// Per-block LDS aggregation + ONE sharded global atomic per block.
__global__ void __launch_bounds__(256)
k_collect(const float* __restrict__ box_cls, const float* __restrict__ ctr_sig,
          const uint32_t* __restrict__ meta, const uint32_t* __restrict__ bmax,
          uint32_t* __restrict__ cnt, uint64_t* __restrict__ cand){
  __shared__ uint64_t buf[LBUF];
  __shared__ uint32_t lcnt;
  __shared__ uint32_t gbase;
  const int n = blockIdx.y;
  const uint32_t T = meta[n * 4 + 1];
  if (bmax[n * HBLK + blockIdx.x] < T) return;   // uniform: no candidate in this block
  if (threadIdx.x == 0) lcnt = 0;
  __syncthreads();
  const float4* cls4 = (const float4*)(box_cls + (size_t)n * NPC);
  const float* cs = ctr_sig + (size_t)n * NPTS;
  const int base4 = blockIdx.x * 1024 + threadIdx.x;
  float4 a[4], b[4];
  int p0a[4], ca[4];
  bool ok[4];
  #pragma unroll
  for (int k = 0; k < 4; ++k){
    int i4 = base4 + k * 256;
    ok[k] = (i4 < NF4);
    if (ok[k]){
      a[k] = cls4[i4];
      uint32_t e0 = (uint32_t)(i4 << 2);
      uint32_t c = e0 / (uint32_t)NPTS;      // constant within a 4-aligned group
      uint32_t p0 = e0 - c * (uint32_t)NPTS;
      ca[k] = (int)c; p0a[k] = (int)p0;
      b[k] = *(const float4*)(cs + p0);
    }
  }
  __builtin_amdgcn_sched_barrier(0);         // keep all 8 loads issued up-front (MLP)
  #pragma unroll
  for (int k = 0; k < 4; ++k){
    if (!ok[k]) continue;
    float sv[4] = {a[k].x, a[k].y, a[k].z, a[k].w};
    float cv[4] = {b[k].x, b[k].y, b[k].z, b[k].w};
    #pragma unroll
    for (int j = 0; j < 4; ++j){
      float s = sigm(sv[j]);
      if (s > 0.05f){
        float sc = s * cv[j];
        if (sc > 0.0f){
          uint32_t bits = __float_as_uint(sc);
          if ((bits >> 18) >= T){
            uint32_t f = (uint32_t)(p0a[k] + j) * NCLS + (uint32_t)ca[k]; // ref flat idx
            uint32_t pos = atomicAdd(&lcnt, 1u);            // LDS atomic: rare
            if (pos < LBUF)
              buf[pos] = ((uint64_t)bits << 32) | (uint64_t)(0xFFFFFFFFu - f);
          }
        }
      }
    }
  }
  __syncthreads();
  uint32_t c = lcnt; if (c > LBUF) c = LBUF;
  const int sh = blockIdx.x & (NSH - 1);
  if (threadIdx.x == 0 && c) gbase = atomicAdd(&cnt[n * NSH + sh], c);  // 1 atomic/block
  __syncthreads();
  for (uint32_t i = threadIdx.x; i < c; i += 256){
    uint32_t p = gbase + i;
    if (p < SHCAP) cand[(((size_t)n * NSH + sh) << 9) + p] = buf[i];
  }
}

// rank-based selection: rank(x) = #{y: key_y > key_x} is x's exact sorted position
// (keys unique: index embedded). Barrier-free LDS broadcast scan.
__global__ void __launch_bounds__(256)
k_rank(const uint32_t* __restrict__ cnt, const uint64_t* __restrict__ cand,
       uint64_t* __restrict__ skey){
  __shared__ alignas(16) uint64_t keys[SORTN + 4];
  __shared__ uint32_t cs_s[NSH], pre_s[NSH + 1];
  const int n = blockIdx.y;
  const int t = threadIdx.x;
  if (t == 0){
    uint32_t acc = 0;
    for (int s = 0; s < NSH; ++s){
      uint32_t c = cnt[n * NSH + s]; if (c > SHCAP) c = SHCAP;
      cs_s[s] = c; pre_s[s] = acc; acc += c;
    }
    pre_s[NSH] = acc;
  }
  __syncthreads();
  const int total = (int)pre_s[NSH];
  const int base = blockIdx.x * 256;
  if (base >= total) return;                 // block-uniform early exit
  for (int i = t; i < SORTN; i += 256){
    int s = i >> 9, j = i & (SHCAP - 1);
    if ((uint32_t)j < cs_s[s])
      keys[pre_s[s] + j] = cand[(((size_t)n * NSH + s) << 9) + j];
  }
  if (t < 4) keys[total + t] = 0ull;         // pad for unroll-4 (0 never outranks)
  __syncthreads();
  const int g = base + t;
  const uint64_t my = (g < total) ? keys[g] : 0ull;
  uint32_t rank = 0;
  const int tot4 = (total + 3) & ~3;
  for (int i = 0; i < tot4; i += 4){         // same-address broadcast reads: conflict-free
    rank += (keys[i]     > my) ? 1u : 0u;
    rank += (keys[i + 1] > my) ? 1u : 0u;
    rank += (keys[i + 2] > my) ? 1u : 0u;
    rank += (keys[i + 3] > my) ? 1u : 0u;
  }
  if (g < total && rank < TOPK)
    skey[(size_t)n * 1024 + rank] = my;      // ranks in [0,total) are a permutation
}

// decode boxes for the 1000 rank-ordered keys (pure decode; partition removed)
__global__ void __launch_bounds__(1024)
k_decode(const uint64_t* __restrict__ skey,
         const float* __restrict__ locations, const float* __restrict__ box_reg,
         const float* __restrict__ im_info,
         float* __restrict__ boxw, float* __restrict__ oboxw, float* __restrict__ scw,
         uint32_t* __restrict__ valw, uint32_t* __restrict__ labw){
  const int n = blockIdx.x;
  const int t = threadIdx.x;
  if (t < TOPK){
    uint64_t kk = skey[(size_t)n * 1024 + t];
    uint32_t bits = (uint32_t)(kk >> 32);
    uint32_t fi = 0xFFFFFFFFu - (uint32_t)(kk & 0xFFFFFFFFull);
    float v = __uint_as_float(bits);
    int loc = 0, ci = 0;
    if (v > 0.0f){ loc = (int)(fi / NCLS); ci = (int)(fi - (uint32_t)loc * NCLS); }
    float px = locations[2 * loc], py = locations[2 * loc + 1];
    const float* rg = box_reg + (size_t)n * 4 * NPTS;
    float rl = rg[loc], rt = rg[NPTS + loc], rr = rg[2 * NPTS + loc], rb = rg[3 * NPTS + loc];
    float h_im = im_info[n * 2 + 0], w_im = im_info[n * 2 + 1];
    float x1 = fminf(fmaxf(px - rl, 0.0f), w_im - 1.0f);
    float y1 = fminf(fmaxf(py - rt, 0.0f), h_im - 1.0f);
    float x2 = fminf(fmaxf(px + rr, 0.0f), w_im - 1.0f);
    float y2 = fminf(fmaxf(py + rb, 0.0f), h_im - 1.0f);
    bool valid = (v > 0.0f) && (__fsub_rn(x2, x1) >= 0.0f) && (__fsub_rn(y2, y1) >= 0.0f);
    float scv = valid ? v : 0.0f;
    float lab = (float)(ci + 1);
    float off = __fmul_rn(lab, 100000.0f);   // CLASS_OFFSET, mul then add (no fma) like ref
    size_t b4 = ((size_t)n * TOPK + t) * 4;
    boxw[b4 + 0] = x1; boxw[b4 + 1] = y1; boxw[b4 + 2] = x2; boxw[b4 + 3] = y2;
    oboxw[b4 + 0] = __fadd_rn(x1, off); oboxw[b4 + 1] = __fadd_rn(y1, off);
    oboxw[b4 + 2] = __fadd_rn(x2, off); oboxw[b4 + 3] = __fadd_rn(y2, off);
    size_t b1 = (size_t)n * TOPK + t;
    scw[b1] = scv; valw[b1] = valid ? 1u : 0u; labw[b1] = (uint32_t)(ci + 1);
  }
}

// greedy NMS per (image,class). Each block builds its own class list via
// ballot-compaction over the 1000 labels (coalesced; order-preserving = stable).
__global__ void __launch_bounds__(64)
k_nms(const uint32_t* __restrict__ labw, const float* __restrict__ oboxw,
      const uint32_t* __restrict__ valw, uint32_t* __restrict__ keepw){
  const int n = blockIdx.y;
  const int c = blockIdx.x;                  // 0-based; label = c+1
  const int L = threadIdx.x;
  __shared__ uint16_t lst_s[TOPK];
  const uint32_t target = (uint32_t)(c + 1);
  uint32_t kcnt = 0;
  for (int i0 = 0; i0 < TOPK; i0 += 64){
    int slot = i0 + L;
    uint32_t lab = (slot < TOPK) ? labw[n * TOPK + slot] : 0u;
    bool m = (lab == target);
    uint64_t mask = __ballot(m);
    uint32_t pre = (uint32_t)__popcll(mask & ((1ull << L) - 1ull));
    if (m) lst_s[kcnt + pre] = (uint16_t)slot;
    kcnt += (uint32_t)__popcll(mask);        // uniform across lanes
  }
  __syncthreads();
  if (kcnt == 0) return;
  if (kcnt <= 64){
    int gi = 0, kp = 0;
    float b0 = 0, b1 = 0, b2 = 0, b3 = 0, ar = 0;
    if (L < (int)kcnt){
      gi = (int)lst_s[L];
      size_t a4 = ((size_t)n * TOPK + gi) * 4;
      b0 = oboxw[a4 + 0]; b1 = oboxw[a4 + 1]; b2 = oboxw[a4 + 2]; b3 = oboxw[a4 + 3];
      kp = (valw[n * TOPK + gi] != 0) ? 1 : 0;
      ar = __fmul_rn(fmaxf(__fsub_rn(b2, b0), 0.0f), fmaxf(__fsub_rn(b3, b1), 0.0f));
    }
    for (int i = 0; i + 1 < (int)kcnt; ++i){
      int alive = __shfl(kp, i);
      float xi0 = __shfl(b0, i), xi1 = __shfl(b1, i), xi2 = __shfl(b2, i), xi3 = __shfl(b3, i);
      float ai = __shfl(ar, i);
      if (alive && L > i && kp){
        float ltx = fmaxf(xi0, b0), lty = fmaxf(xi1, b1);
        float rbx = fminf(xi2, b2), rby = fminf(xi3, b3);
        float w = fmaxf(__fsub_rn(rbx, ltx), 0.0f);
        float h = fmaxf(__fsub_rn(rby, lty), 0.0f);
        float inter = __fmul_rn(w, h);
        float den = __fadd_rn(__fsub_rn(__fadd_rn(ai, ar), inter), 1e-9f);
        if (inter / den > 0.6f) kp = 0;
      }
    }
    if (L < (int)kcnt) keepw[n * TOPK + gi] = (uint32_t)kp;
  } else if (L == 0){
    // slow path (kcnt > 64): sequential, correctness-only (statistically never hit)
    for (uint32_t i = 0; i < kcnt; ++i){
      int gi = (int)lst_s[i];
      keepw[n * TOPK + gi] = valw[n * TOPK + gi];
    }
    for (uint32_t i = 0; i < kcnt; ++i){
      int gi = (int)lst_s[i];
      if (!keepw[n * TOPK + gi]) continue;
      size_t a4 = ((size_t)n * TOPK + gi) * 4;
      float x0 = oboxw[a4], x1 = oboxw[a4 + 1], x2 = oboxw[a4 + 2], x3 = oboxw[a4 + 3];
      float ai = __fmul_rn(fmaxf(__fsub_rn(x2, x0), 0.0f), fmaxf(__fsub_rn(x3, x1), 0.0f));
      for (uint32_t j = i + 1; j < kcnt; ++j){
        int gj = (int)lst_s[j];
        if (!keepw[n * TOPK + gj]) continue;
        size_t c4 = ((size_t)n * TOPK + gj) * 4;
        float y0 = oboxw[c4], y1 = oboxw[c4 + 1], y2 = oboxw[c4 + 2], y3 = oboxw[c4 + 3];
        float aj = __fmul_rn(fmaxf(__fsub_rn(y2, y0), 0.0f), fmaxf(__fsub_rn(y3, y1), 0.0f));
        float ltx = fmaxf(x0, y0), lty = fmaxf(x1, y1);
        float rbx = fminf(x2, y2), rby = fminf(x3, y3);
        float w = fmaxf(__fsub_rn(rbx, ltx), 0.0f);
        float h = fmaxf(__fsub_rn(rby, lty), 0.0f);
        float inter = __fmul_rn(w, h);
        float den = __fadd_rn(__fsub_rn(__fadd_rn(ai, aj), inter), 1e-9f);
        if (inter / den > 0.6f) keepw[n * TOPK + gj] = 0;
      }
    }
  }
}

// compact kept (already score-sorted) entries via parallel prefix scan; first 100 rows out
__global__ void __launch_bounds__(256)
k_final(const uint32_t* __restrict__ keepw, const float* __restrict__ boxw,
        const uint32_t* __restrict__ labw, const float* __restrict__ scw,
        float* __restrict__ out){
  const int n = blockIdx.x;
  __shared__ uint16_t fi_s[TOPK];
  __shared__ uint32_t wsum[4];
  const int t = threadIdx.x;
  const int i0 = t * 4;
  uint32_t f[4];
  #pragma unroll
  for (int j = 0; j < 4; ++j)
    f[j] = (i0 + j < TOPK) ? keepw[n * TOPK + i0 + j] : 0u;
  uint32_t lsum = f[0] + f[1] + f[2] + f[3];
  uint32_t sc = lsum;
  #pragma unroll
  for (int d = 1; d < 64; d <<= 1){
    uint32_t v = __shfl_up(sc, d);
    if ((t & 63) >= d) sc += v;
  }
  if ((t & 63) == 63) wsum[t >> 6] = sc;
  __syncthreads();
  uint32_t base = sc - lsum;
  for (int w = 0; w < (t >> 6); ++w) base += wsum[w];
  uint32_t p = base;
  #pragma unroll
  for (int j = 0; j < 4; ++j){
    if (f[j]){ if (p < TOPK) fi_s[p] = (uint16_t)(i0 + j); ++p; }
  }
  __syncthreads();
  uint32_t total = wsum[0] + wsum[1] + wsum[2] + wsum[3];
  if (t < POSTK){
    float* row = out + ((size_t)n * POSTK + t) * 6;
    if (t < (int)total){
      int i = (int)fi_s[t];
      size_t b4 = ((size_t)n * TOPK + i) * 4;
      row[0] = boxw[b4]; row[1] = boxw[b4 + 1]; row[2] = boxw[b4 + 2]; row[3] = boxw[b4 + 3];
      row[4] = (float)labw[n * TOPK + i]; row[5] = scw[n * TOPK + i];
    } else {
      row[0] = 0.0f; row[1] = 0.0f; row[2] = 0.0f;
      row[3] = 0.0f; row[4] = 0.0f; row[5] = 0.0f;
    }
  }
}

extern "C" void kernel_launch(void* const* d_in, const int* in_sizes, int n_in,
                              void* d_out, int out_size, void* d_ws, size_t ws_size,
                              hipStream_t stream){
  const float* locations = (const float*)d_in[0];
  const float* box_cls   = (const float*)d_in[1];
  const float* box_reg   = (const float*)d_in[2];
  const float* ctr       = (const float*)d_in[3];
  const float* im_info   = (const float*)d_in[4];
  float* out = (float*)d_out;
  char* ws = (char*)d_ws;
  uint32_t* h1    = (uint32_t*)(ws + B_H1);
  uint32_t* cnt   = (uint32_t*)(ws + B_CNT);
  uint32_t* meta  = (uint32_t*)(ws + B_META);
  uint32_t* bmax  = (uint32_t*)(ws + B_BMAX);
  uint64_t* skey  = (uint64_t*)(ws + B_SKEY);
  float*    ctrs  = (float*)(ws + B_CTRS);
  uint64_t* cand  = (uint64_t*)(ws + B_CAND);
  float*    boxw  = (float*)(ws + B_BOX);
  float*    oboxw = (float*)(ws + B_OBOX);
  float*    scw   = (float*)(ws + B_SC);
  uint32_t* valw  = (uint32_t*)(ws + B_VAL);
  uint32_t* labw  = (uint32_t*)(ws + B_LAB);
  uint32_t* keepw = (uint32_t*)(ws + B_KEEP);

  hipMemsetAsync(d_ws, 0, B_ZEND, stream);
  k_ctrsig<<<dim3((NIMG*NPTS/4 + 255)/256), 256, 0, stream>>>(ctr, ctrs);
  dim3 scang(HBLK, NIMG);
  k_hist<<<scang, 256, 0, stream>>>(box_cls, ctrs, h1, bmax);
  k_scan<<<NIMG, 256, 0, stream>>>(h1, meta);
  k_collect<<<scang, 256, 0, stream>>>(box_cls, ctrs, meta, bmax, cnt, cand);
  k_rank<<<dim3(RBLK, NIMG), 256, 0, stream>>>(cnt, cand, skey);
  k_decode<<<NIMG, 1024, 0, stream>>>(skey, locations, box_reg, im_info,
                                      boxw, oboxw, scw, valw, labw);
  k_nms<<<dim3(NCLS, NIMG), 64, 0, stream>>>(labw, oboxw, valw, keepw);
  k_final<<<NIMG, 256, 0, stream>>>(keepw, boxw, labw, scw, out);
}